// Round 6
// baseline (605.684 us; speedup 1.0000x reference)
//
#include <hip/hip_runtime.h>
#include <math.h>

#define EMB 64

typedef float f32x4 __attribute__((ext_vector_type(4)));
typedef int   i32x4 __attribute__((ext_vector_type(4)));

// ---------- CSR build ----------

// one pass: count AND per-edge rank (rank = atomicAdd return). 4 edges/thread.
__global__ void count_rank_k(const int* __restrict__ el, int* __restrict__ cnt,
                             int* __restrict__ rank, int n4, int n) {
    int i = blockIdx.x * blockDim.x + threadIdx.x;
    if (i >= n4) return;
    int base = i * 4;
    i32x4 e = __builtin_nontemporal_load(reinterpret_cast<const i32x4*>(el) + i);
    i32x4 r;
    r.x = atomicAdd(cnt + e.x, 1);
    r.y = (base + 1 < n) ? atomicAdd(cnt + e.y, 1) : 0;
    r.z = (base + 2 < n) ? atomicAdd(cnt + e.z, 1) : 0;
    r.w = (base + 3 < n) ? atomicAdd(cnt + e.w, 1) : 0;
    __builtin_nontemporal_store(r, reinterpret_cast<i32x4*>(rank) + i);
}

__global__ void block_sum_k(const int* __restrict__ cnt, int* __restrict__ part, int n) {
    __shared__ int s[256];
    int i = blockIdx.x * 256 + threadIdx.x;
    s[threadIdx.x] = (i < n) ? cnt[i] : 0;
    __syncthreads();
    for (int off = 128; off > 0; off >>= 1) {
        if (threadIdx.x < off) s[threadIdx.x] += s[threadIdx.x + off];
        __syncthreads();
    }
    if (threadIdx.x == 0) part[blockIdx.x] = s[0];
}

// single-block exclusive scan of nb (<=4096) partials, 1024 threads
__global__ void scan_part_k(int* __restrict__ part, int nb) {
    __shared__ int s[4096];
    for (int i = threadIdx.x; i < 4096; i += 1024) s[i] = (i < nb) ? part[i] : 0;
    __syncthreads();
    for (int off = 1; off < 4096; off <<= 1) {
        int vals[4];
        #pragma unroll
        for (int j = 0; j < 4; ++j) {
            int i = threadIdx.x + j * 1024;
            vals[j] = (i >= off) ? s[i - off] : 0;
        }
        __syncthreads();
        #pragma unroll
        for (int j = 0; j < 4; ++j) {
            int i = threadIdx.x + j * 1024;
            s[i] += vals[j];
        }
        __syncthreads();
    }
    for (int i = threadIdx.x; i < nb; i += 1024) part[i] = (i == 0) ? 0 : s[i - 1];
}

// writes meta[i] = (exclusive_offset, count) as int2
__global__ void scan_meta_k(const int* __restrict__ cnt, const int* __restrict__ part,
                            int2* __restrict__ meta, int n) {
    __shared__ int s[256];
    int i = blockIdx.x * 256 + threadIdx.x;
    int v = (i < n) ? cnt[i] : 0;
    s[threadIdx.x] = v;
    __syncthreads();
    for (int off = 1; off < 256; off <<= 1) {
        int t = (threadIdx.x >= (unsigned)off) ? s[threadIdx.x - off] : 0;
        __syncthreads();
        s[threadIdx.x] += t;
        __syncthreads();
    }
    if (i < n) {
        int2 m;
        m.x = s[threadIdx.x] - v + part[blockIdx.x];
        m.y = v;
        meta[i] = m;
    }
}

// atomic-free fill using precomputed ranks; 4 edges/thread
__global__ void fill_csr_k(const int* __restrict__ el, const int* __restrict__ rank,
                           const int2* __restrict__ meta, int* __restrict__ csr,
                           int n4, int n) {
    int i = blockIdx.x * blockDim.x + threadIdx.x;
    if (i >= n4) return;
    int base = i * 4;
    i32x4 e = __builtin_nontemporal_load(reinterpret_cast<const i32x4*>(el) + i);
    i32x4 r = __builtin_nontemporal_load(reinterpret_cast<const i32x4*>(rank) + i);
    csr[meta[e.x].x + r.x] = base;
    if (base + 1 < n) csr[meta[e.y].x + r.y] = base + 1;
    if (base + 2 < n) csr[meta[e.z].x + r.z] = base + 2;
    if (base + 3 < n) csr[meta[e.w].x + r.w] = base + 3;
}

// ---------- gather: 16 lanes per group, TWO locs per group, 8 rows/loc in flight ----------

__device__ __forceinline__ f32x4 ld_row_nt(const float* noise, int e, int q) {
    const f32x4* p = reinterpret_cast<const f32x4*>(noise + ((long long)e << 6)) + q;
    return __builtin_nontemporal_load(p);
}

__global__ void gather2_k(const float* __restrict__ loc_emb, const float* __restrict__ noise,
                          const int* __restrict__ meta, const int* __restrict__ csr,
                          float* __restrict__ out, float sigma, int n_locs, int n_edges) {
    int gid = blockIdx.x * blockDim.x + threadIdx.x;
    int g = gid >> 4;          // group handles locs 2g, 2g+1
    int q = gid & 15;
    int loc0 = g * 2;
    if (loc0 >= n_locs) return;
    // (offs0, c0, offs1, c1) in one 16B load
    i32x4 m = *(reinterpret_cast<const i32x4*>(meta) + g);
    int st0 = m.x, c0 = m.y, st1 = m.z, c1 = m.w;
    int cmax = c0 > c1 ? c0 : c1;
    int l0 = c0 > 0 ? c0 - 1 : 0;
    int l1 = c1 > 0 ? c1 - 1 : 0;
    f32x4 a0 = (f32x4)(0.f), a1 = (f32x4)(0.f);
    for (int i = 0; i < cmax; i += 8) {
        int e0[8], e1[8];
        #pragma unroll
        for (int j = 0; j < 8; ++j) {
            int i0 = i + j;
            int k0 = st0 + (i0 < l0 ? i0 : l0);
            int k1 = st1 + (i0 < l1 ? i0 : l1);
            int t0 = csr[k0];
            int t1 = csr[k1];
            e0[j] = ((unsigned)t0 < (unsigned)n_edges) ? t0 : 0;
            e1[j] = ((unsigned)t1 < (unsigned)n_edges) ? t1 : 0;
        }
        f32x4 v0[8], v1[8];
        #pragma unroll
        for (int j = 0; j < 8; ++j) {
            v0[j] = ld_row_nt(noise, e0[j], q);
            v1[j] = ld_row_nt(noise, e1[j], q);
        }
        #pragma unroll
        for (int j = 0; j < 8; ++j) {
            if (i + j < c0) a0 += v0[j];
            if (i + j < c1) a1 += v1[j];
        }
    }
    float s0 = (c0 > 0) ? sigma / (float)c0 : 0.f;
    float s1 = (c1 > 0) ? sigma / (float)c1 : 0.f;
    long long base = ((long long)loc0 << 6) + (q << 2);
    f32x4 b0 = __builtin_nontemporal_load(reinterpret_cast<const f32x4*>(loc_emb + base));
    f32x4 o0 = b0 + s0 * a0;
    __builtin_nontemporal_store(o0, reinterpret_cast<f32x4*>(out + base));
    if (loc0 + 1 < n_locs) {
        f32x4 b1 = __builtin_nontemporal_load(reinterpret_cast<const f32x4*>(loc_emb + base + EMB));
        f32x4 o1 = b1 + s1 * a1;
        __builtin_nontemporal_store(o1, reinterpret_cast<f32x4*>(out + base + EMB));
    }
}

extern "C" void kernel_launch(void* const* d_in, const int* in_sizes, int n_in,
                              void* d_out, int out_size, void* d_ws, size_t ws_size,
                              hipStream_t stream) {
    const float* loc_emb = (const float*)d_in[0];
    const float* noise   = (const float*)d_in[1];
    const int*   el      = (const int*)d_in[2];
    float* out = (float*)d_out;

    int n_locs  = in_sizes[0] / EMB;
    int n_edges = in_sizes[2];

    // workspace layout (all 16B-aligned)
    char* w = (char*)d_ws;
    int*  cnt  = (int*)w;                 w += (size_t)n_locs * sizeof(int);
    int*  part = (int*)w;                 w += 4096 * sizeof(int);
    int2* meta = (int2*)w;                w += (size_t)n_locs * sizeof(int2);
    int*  rank = (int*)w;                 w += (size_t)n_edges * sizeof(int);
    int*  csr  = (int*)w;

    int nb = (n_locs + 255) / 256;
    int n4 = (n_edges + 3) / 4;

    (void)hipMemsetAsync(cnt, 0, (size_t)n_locs * sizeof(int), stream);

    count_rank_k<<<(n4 + 255) / 256, 256, 0, stream>>>(el, cnt, rank, n4, n_edges);
    block_sum_k<<<nb, 256, 0, stream>>>(cnt, part, n_locs);
    scan_part_k<<<1, 1024, 0, stream>>>(part, nb);
    scan_meta_k<<<nb, 256, 0, stream>>>(cnt, part, meta, n_locs);
    fill_csr_k<<<(n4 + 255) / 256, 256, 0, stream>>>(el, rank, meta, csr, n4, n_edges);

    double sigma = 1.0 * sqrt(2.0 * log(1.25 / 1e-5)) / 1.0;
    int n_groups = (n_locs + 1) / 2;              // 2 locs per 16-lane group
    long long total = (long long)n_groups * 16;
    int blocks = (int)((total + 255) / 256);
    gather2_k<<<blocks, 256, 0, stream>>>(loc_emb, noise, (const int*)meta, csr, out,
                                          (float)sigma, n_locs, n_edges);
}

// Round 7
// 556.169 us; speedup vs baseline: 1.0890x; 1.0890x over previous
//
#include <hip/hip_runtime.h>
#include <math.h>

#define EMB 64

typedef float f32x4 __attribute__((ext_vector_type(4)));
typedef int   i32x4 __attribute__((ext_vector_type(4)));

// ---------- CSR build ----------

// one pass: count AND per-edge rank (rank = atomicAdd return). 4 edges/thread.
// el/rank kept CACHED: both are re-read by fill_csr_k and fit in L3.
__global__ void count_rank_k(const int* __restrict__ el, int* __restrict__ cnt,
                             int* __restrict__ rank, int n4, int n) {
    int i = blockIdx.x * blockDim.x + threadIdx.x;
    if (i >= n4) return;
    int base = i * 4;
    i32x4 e = *(reinterpret_cast<const i32x4*>(el) + i);
    i32x4 r;
    r.x = atomicAdd(cnt + e.x, 1);
    r.y = (base + 1 < n) ? atomicAdd(cnt + e.y, 1) : 0;
    r.z = (base + 2 < n) ? atomicAdd(cnt + e.z, 1) : 0;
    r.w = (base + 3 < n) ? atomicAdd(cnt + e.w, 1) : 0;
    *(reinterpret_cast<i32x4*>(rank) + i) = r;
}

__global__ void block_sum_k(const int* __restrict__ cnt, int* __restrict__ part, int n) {
    __shared__ int s[256];
    int i = blockIdx.x * 256 + threadIdx.x;
    s[threadIdx.x] = (i < n) ? cnt[i] : 0;
    __syncthreads();
    for (int off = 128; off > 0; off >>= 1) {
        if (threadIdx.x < off) s[threadIdx.x] += s[threadIdx.x + off];
        __syncthreads();
    }
    if (threadIdx.x == 0) part[blockIdx.x] = s[0];
}

// single-block exclusive scan of nb (<=4096) partials, 1024 threads
__global__ void scan_part_k(int* __restrict__ part, int nb) {
    __shared__ int s[4096];
    for (int i = threadIdx.x; i < 4096; i += 1024) s[i] = (i < nb) ? part[i] : 0;
    __syncthreads();
    for (int off = 1; off < 4096; off <<= 1) {
        int vals[4];
        #pragma unroll
        for (int j = 0; j < 4; ++j) {
            int i = threadIdx.x + j * 1024;
            vals[j] = (i >= off) ? s[i - off] : 0;
        }
        __syncthreads();
        #pragma unroll
        for (int j = 0; j < 4; ++j) {
            int i = threadIdx.x + j * 1024;
            s[i] += vals[j];
        }
        __syncthreads();
    }
    for (int i = threadIdx.x; i < nb; i += 1024) part[i] = (i == 0) ? 0 : s[i - 1];
}

// writes meta[i] = (exclusive_offset, count) as int2
__global__ void scan_meta_k(const int* __restrict__ cnt, const int* __restrict__ part,
                            int2* __restrict__ meta, int n) {
    __shared__ int s[256];
    int i = blockIdx.x * 256 + threadIdx.x;
    int v = (i < n) ? cnt[i] : 0;
    s[threadIdx.x] = v;
    __syncthreads();
    for (int off = 1; off < 256; off <<= 1) {
        int t = (threadIdx.x >= (unsigned)off) ? s[threadIdx.x - off] : 0;
        __syncthreads();
        s[threadIdx.x] += t;
        __syncthreads();
    }
    if (i < n) {
        int2 m;
        m.x = s[threadIdx.x] - v + part[blockIdx.x];
        m.y = v;
        meta[i] = m;
    }
}

// atomic-free fill using precomputed ranks; 4 edges/thread; el/rank hit L3
__global__ void fill_csr_k(const int* __restrict__ el, const int* __restrict__ rank,
                           const int2* __restrict__ meta, int* __restrict__ csr,
                           int n4, int n) {
    int i = blockIdx.x * blockDim.x + threadIdx.x;
    if (i >= n4) return;
    int base = i * 4;
    i32x4 e = *(reinterpret_cast<const i32x4*>(el) + i);
    i32x4 r = *(reinterpret_cast<const i32x4*>(rank) + i);
    csr[meta[e.x].x + r.x] = base;
    if (base + 1 < n) csr[meta[e.y].x + r.y] = base + 1;
    if (base + 2 < n) csr[meta[e.z].x + r.z] = base + 2;
    if (base + 3 < n) csr[meta[e.w].x + r.w] = base + 3;
}

// ---------- gather: 16 lanes per location, float4 per lane, 8 rows in flight ----------

__device__ __forceinline__ f32x4 ld_row(const float* noise, int e, int q) {
    // plain (cached) load: clamped duplicate tail loads hit L1, no extra DRAM traffic
    return *(reinterpret_cast<const f32x4*>(noise + ((long long)e << 6)) + q);
}

__global__ void gather_k(const float* __restrict__ loc_emb, const float* __restrict__ noise,
                         const int2* __restrict__ meta, const int* __restrict__ csr,
                         float* __restrict__ out, float sigma, int n_locs) {
    int gid = blockIdx.x * blockDim.x + threadIdx.x;
    int loc = gid >> 4;
    if (loc >= n_locs) return;
    int q = gid & 15;
    int2 m = meta[loc];               // one 8B load: (offset, count)
    int st = m.x, c = m.y;
    f32x4 acc = (f32x4)(0.f);
    for (int i = 0; i < c; i += 8) {
        int r = c - i;          // >= 1
        int b0 = st + i;
        int e[8];
        #pragma unroll
        for (int j = 0; j < 8; ++j)
            e[j] = csr[b0 + (j < r ? j : r - 1)];   // clamped, in-bounds
        f32x4 v[8];
        #pragma unroll
        for (int j = 0; j < 8; ++j)
            v[j] = ld_row(noise, e[j], q);          // 8 independent 256B rows in flight
        #pragma unroll
        for (int j = 0; j < 8; ++j)
            if (j < r) acc += v[j];
    }
    float s = (c > 0) ? sigma / (float)c : 0.f;
    const f32x4* bp = reinterpret_cast<const f32x4*>(loc_emb + ((long long)loc << 6)) + q;
    f32x4 b = __builtin_nontemporal_load(bp);
    f32x4 o = b + s * acc;
    f32x4* op = reinterpret_cast<f32x4*>(out + ((long long)loc << 6)) + q;
    __builtin_nontemporal_store(o, op);
}

extern "C" void kernel_launch(void* const* d_in, const int* in_sizes, int n_in,
                              void* d_out, int out_size, void* d_ws, size_t ws_size,
                              hipStream_t stream) {
    const float* loc_emb = (const float*)d_in[0];
    const float* noise   = (const float*)d_in[1];
    const int*   el      = (const int*)d_in[2];
    float* out = (float*)d_out;

    int n_locs  = in_sizes[0] / EMB;
    int n_edges = in_sizes[2];

    // workspace layout (all 16B-aligned)
    char* w = (char*)d_ws;
    int*  cnt  = (int*)w;                 w += (size_t)n_locs * sizeof(int);
    int*  part = (int*)w;                 w += 4096 * sizeof(int);
    int2* meta = (int2*)w;                w += (size_t)n_locs * sizeof(int2);
    int*  rank = (int*)w;                 w += (size_t)n_edges * sizeof(int);
    int*  csr  = (int*)w;

    int nb = (n_locs + 255) / 256;
    int n4 = (n_edges + 3) / 4;

    (void)hipMemsetAsync(cnt, 0, (size_t)n_locs * sizeof(int), stream);

    count_rank_k<<<(n4 + 255) / 256, 256, 0, stream>>>(el, cnt, rank, n4, n_edges);
    block_sum_k<<<nb, 256, 0, stream>>>(cnt, part, n_locs);
    scan_part_k<<<1, 1024, 0, stream>>>(part, nb);
    scan_meta_k<<<nb, 256, 0, stream>>>(cnt, part, meta, n_locs);
    fill_csr_k<<<(n4 + 255) / 256, 256, 0, stream>>>(el, rank, meta, csr, n4, n_edges);

    double sigma = 1.0 * sqrt(2.0 * log(1.25 / 1e-5)) / 1.0;
    long long total = (long long)n_locs * 16;
    int blocks = (int)((total + 255) / 256);
    gather_k<<<blocks, 256, 0, stream>>>(loc_emb, noise, meta, csr, out,
                                         (float)sigma, n_locs);
}

// Round 8
// 552.626 us; speedup vs baseline: 1.0960x; 1.0064x over previous
//
#include <hip/hip_runtime.h>
#include <math.h>

#define EMB 64

typedef float f32x4 __attribute__((ext_vector_type(4)));

// ---------- CSR build ----------

// one pass: count AND per-edge rank (rank = atomicAdd return). 1 edge/thread
// (max atomic parallelism — 4-edges/thread serialized its atomics and lost).
__global__ void count_rank_k(const int* __restrict__ el, int* __restrict__ cnt,
                             int* __restrict__ rank, int n) {
    int i = blockIdx.x * blockDim.x + threadIdx.x;
    if (i < n) rank[i] = atomicAdd(cnt + el[i], 1);
}

__global__ void block_sum_k(const int* __restrict__ cnt, int* __restrict__ part, int n) {
    __shared__ int s[256];
    int i = blockIdx.x * 256 + threadIdx.x;
    s[threadIdx.x] = (i < n) ? cnt[i] : 0;
    __syncthreads();
    for (int off = 128; off > 0; off >>= 1) {
        if (threadIdx.x < off) s[threadIdx.x] += s[threadIdx.x + off];
        __syncthreads();
    }
    if (threadIdx.x == 0) part[blockIdx.x] = s[0];
}

// single-block exclusive scan of nb (<=4096) partials, 1024 threads
__global__ void scan_part_k(int* __restrict__ part, int nb) {
    __shared__ int s[4096];
    for (int i = threadIdx.x; i < 4096; i += 1024) s[i] = (i < nb) ? part[i] : 0;
    __syncthreads();
    for (int off = 1; off < 4096; off <<= 1) {
        int vals[4];
        #pragma unroll
        for (int j = 0; j < 4; ++j) {
            int i = threadIdx.x + j * 1024;
            vals[j] = (i >= off) ? s[i - off] : 0;
        }
        __syncthreads();
        #pragma unroll
        for (int j = 0; j < 4; ++j) {
            int i = threadIdx.x + j * 1024;
            s[i] += vals[j];
        }
        __syncthreads();
    }
    for (int i = threadIdx.x; i < nb; i += 1024) part[i] = (i == 0) ? 0 : s[i - 1];
}

// writes meta[i] = (exclusive_offset, count) as int2
__global__ void scan_meta_k(const int* __restrict__ cnt, const int* __restrict__ part,
                            int2* __restrict__ meta, int n) {
    __shared__ int s[256];
    int i = blockIdx.x * 256 + threadIdx.x;
    int v = (i < n) ? cnt[i] : 0;
    s[threadIdx.x] = v;
    __syncthreads();
    for (int off = 1; off < 256; off <<= 1) {
        int t = (threadIdx.x >= (unsigned)off) ? s[threadIdx.x - off] : 0;
        __syncthreads();
        s[threadIdx.x] += t;
        __syncthreads();
    }
    if (i < n) {
        int2 m;
        m.x = s[threadIdx.x] - v + part[blockIdx.x];
        m.y = v;
        meta[i] = m;
    }
}

// atomic-free fill using precomputed ranks; 1 edge/thread
__global__ void fill_csr_k(const int* __restrict__ el, const int* __restrict__ rank,
                           const int2* __restrict__ meta, int* __restrict__ csr, int n) {
    int i = blockIdx.x * blockDim.x + threadIdx.x;
    if (i < n) csr[meta[el[i]].x + rank[i]] = i;
}

// ---------- gather: 16 lanes per location, float4 per lane ----------
// masked NT noise loads: no duplicate fetches, and the 1 GB zero-reuse noise
// stream bypasses L3 so csr/meta stay cache-resident.

__device__ __forceinline__ f32x4 ld_row_nt(const float* noise, int e, int q) {
    const f32x4* p = reinterpret_cast<const f32x4*>(noise + ((long long)e << 6)) + q;
    return __builtin_nontemporal_load(p);
}

__global__ void gather_k(const float* __restrict__ loc_emb, const float* __restrict__ noise,
                         const int2* __restrict__ meta, const int* __restrict__ csr,
                         float* __restrict__ out, float sigma, int n_locs) {
    int gid = blockIdx.x * blockDim.x + threadIdx.x;
    int loc = gid >> 4;
    if (loc >= n_locs) return;
    int q = gid & 15;
    int2 m = meta[loc];               // one 8B load: (offset, count)
    int st = m.x, c = m.y;
    // hoist the independent emb load so it overlaps the meta->csr->noise chain
    const f32x4* bp = reinterpret_cast<const f32x4*>(loc_emb + ((long long)loc << 6)) + q;
    f32x4 b = __builtin_nontemporal_load(bp);
    f32x4 acc = (f32x4)(0.f);
    for (int i = 0; i < c; i += 8) {
        int r = c - i;          // >= 1
        int b0 = st + i;
        int e[8];
        f32x4 v[8];
        #pragma unroll
        for (int j = 0; j < 8; ++j)
            if (j < r) e[j] = csr[b0 + j];
        #pragma unroll
        for (int j = 0; j < 8; ++j)
            if (j < r) v[j] = ld_row_nt(noise, e[j], q);   // up to 8 rows in flight
        #pragma unroll
        for (int j = 0; j < 8; ++j)
            if (j < r) acc += v[j];
    }
    float s = (c > 0) ? sigma / (float)c : 0.f;
    f32x4 o = b + s * acc;
    f32x4* op = reinterpret_cast<f32x4*>(out + ((long long)loc << 6)) + q;
    __builtin_nontemporal_store(o, op);
}

extern "C" void kernel_launch(void* const* d_in, const int* in_sizes, int n_in,
                              void* d_out, int out_size, void* d_ws, size_t ws_size,
                              hipStream_t stream) {
    const float* loc_emb = (const float*)d_in[0];
    const float* noise   = (const float*)d_in[1];
    const int*   el      = (const int*)d_in[2];
    float* out = (float*)d_out;

    int n_locs  = in_sizes[0] / EMB;
    int n_edges = in_sizes[2];

    // workspace layout (all 16B-aligned)
    char* w = (char*)d_ws;
    int*  cnt  = (int*)w;                 w += (size_t)n_locs * sizeof(int);
    int*  part = (int*)w;                 w += 4096 * sizeof(int);
    int2* meta = (int2*)w;                w += (size_t)n_locs * sizeof(int2);
    int*  rank = (int*)w;                 w += (size_t)n_edges * sizeof(int);
    int*  csr  = (int*)w;

    int nb = (n_locs + 255) / 256;

    (void)hipMemsetAsync(cnt, 0, (size_t)n_locs * sizeof(int), stream);

    count_rank_k<<<(n_edges + 255) / 256, 256, 0, stream>>>(el, cnt, rank, n_edges);
    block_sum_k<<<nb, 256, 0, stream>>>(cnt, part, n_locs);
    scan_part_k<<<1, 1024, 0, stream>>>(part, nb);
    scan_meta_k<<<nb, 256, 0, stream>>>(cnt, part, meta, n_locs);
    fill_csr_k<<<(n_edges + 255) / 256, 256, 0, stream>>>(el, rank, meta, csr, n_edges);

    double sigma = 1.0 * sqrt(2.0 * log(1.25 / 1e-5)) / 1.0;
    long long total = (long long)n_locs * 16;
    int blocks = (int)((total + 255) / 256);
    gather_k<<<blocks, 256, 0, stream>>>(loc_emb, noise, meta, csr, out,
                                         (float)sigma, n_locs);
}

// Round 9
// 538.310 us; speedup vs baseline: 1.1252x; 1.0266x over previous
//
#include <hip/hip_runtime.h>
#include <math.h>

#define EMB 64

typedef float f32x4 __attribute__((ext_vector_type(4)));

// ---------- CSR build ----------

// one pass: count AND per-edge rank (rank = atomicAdd return). 1 edge/thread.
__global__ void count_rank_k(const int* __restrict__ el, int* __restrict__ cnt,
                             int* __restrict__ rank, int n) {
    int i = blockIdx.x * blockDim.x + threadIdx.x;
    if (i < n) rank[i] = atomicAdd(cnt + el[i], 1);
}

__global__ void block_sum_k(const int* __restrict__ cnt, int* __restrict__ part, int n) {
    __shared__ int s[256];
    int i = blockIdx.x * 256 + threadIdx.x;
    s[threadIdx.x] = (i < n) ? cnt[i] : 0;
    __syncthreads();
    for (int off = 128; off > 0; off >>= 1) {
        if (threadIdx.x < off) s[threadIdx.x] += s[threadIdx.x + off];
        __syncthreads();
    }
    if (threadIdx.x == 0) part[blockIdx.x] = s[0];
}

// single-block exclusive scan of nb (<=4096) partials, 1024 threads
__global__ void scan_part_k(int* __restrict__ part, int nb) {
    __shared__ int s[4096];
    for (int i = threadIdx.x; i < 4096; i += 1024) s[i] = (i < nb) ? part[i] : 0;
    __syncthreads();
    for (int off = 1; off < 4096; off <<= 1) {
        int vals[4];
        #pragma unroll
        for (int j = 0; j < 4; ++j) {
            int i = threadIdx.x + j * 1024;
            vals[j] = (i >= off) ? s[i - off] : 0;
        }
        __syncthreads();
        #pragma unroll
        for (int j = 0; j < 4; ++j) {
            int i = threadIdx.x + j * 1024;
            s[i] += vals[j];
        }
        __syncthreads();
    }
    for (int i = threadIdx.x; i < nb; i += 1024) part[i] = (i == 0) ? 0 : s[i - 1];
}

// writes offs[i] (for fill: dense 4B random reads) and meta[i]=(offs,cnt) (for gather)
__global__ void scan_meta_k(const int* __restrict__ cnt, const int* __restrict__ part,
                            int* __restrict__ offs, int2* __restrict__ meta, int n) {
    __shared__ int s[256];
    int i = blockIdx.x * 256 + threadIdx.x;
    int v = (i < n) ? cnt[i] : 0;
    s[threadIdx.x] = v;
    __syncthreads();
    for (int off = 1; off < 256; off <<= 1) {
        int t = (threadIdx.x >= (unsigned)off) ? s[threadIdx.x - off] : 0;
        __syncthreads();
        s[threadIdx.x] += t;
        __syncthreads();
    }
    if (i < n) {
        int excl = s[threadIdx.x] - v + part[blockIdx.x];
        offs[i] = excl;
        int2 m; m.x = excl; m.y = v;
        meta[i] = m;
    }
}

// atomic-free fill using precomputed ranks; 1 edge/thread
__global__ void fill_csr_k(const int* __restrict__ el, const int* __restrict__ rank,
                           const int* __restrict__ offs, int* __restrict__ csr, int n) {
    int i = blockIdx.x * blockDim.x + threadIdx.x;
    if (i < n) csr[offs[el[i]] + rank[i]] = i;
}

// ---------- gather: 16 lanes per location, float4 per lane, 8 rows in flight ----------

__device__ __forceinline__ f32x4 ld_row(const float* noise, int e, int q) {
    // plain (cached) load: clamped duplicate tail loads hit L1, no extra DRAM traffic
    return *(reinterpret_cast<const f32x4*>(noise + ((long long)e << 6)) + q);
}

__global__ __launch_bounds__(256, 8)
void gather_k(const float* __restrict__ loc_emb, const float* __restrict__ noise,
              const int2* __restrict__ meta, const int* __restrict__ csr,
              float* __restrict__ out, float sigma, int n_locs) {
    int gid = blockIdx.x * blockDim.x + threadIdx.x;
    int loc = gid >> 4;
    if (loc >= n_locs) return;
    int q = gid & 15;
    int2 m = meta[loc];               // one 8B load: (offset, count)
    int st = m.x, c = m.y;
    // hoist the independent emb load so it overlaps the meta->csr->noise chain
    const f32x4* bp = reinterpret_cast<const f32x4*>(loc_emb + ((long long)loc << 6)) + q;
    f32x4 b = __builtin_nontemporal_load(bp);
    f32x4 acc = (f32x4)(0.f);
    for (int i = 0; i < c; i += 8) {
        int r = c - i;          // >= 1
        int b0 = st + i;
        int e[8];
        #pragma unroll
        for (int j = 0; j < 8; ++j)
            e[j] = csr[b0 + (j < r ? j : r - 1)];   // clamped, in-bounds (broadcast dups free)
        f32x4 v[8];
        #pragma unroll
        for (int j = 0; j < 8; ++j)
            v[j] = ld_row(noise, e[j], q);          // 8 independent 256B rows in flight
        #pragma unroll
        for (int j = 0; j < 8; ++j)
            if (j < r) acc += v[j];
    }
    float s = (c > 0) ? sigma / (float)c : 0.f;
    f32x4 o = b + s * acc;
    f32x4* op = reinterpret_cast<f32x4*>(out + ((long long)loc << 6)) + q;
    __builtin_nontemporal_store(o, op);
}

extern "C" void kernel_launch(void* const* d_in, const int* in_sizes, int n_in,
                              void* d_out, int out_size, void* d_ws, size_t ws_size,
                              hipStream_t stream) {
    const float* loc_emb = (const float*)d_in[0];
    const float* noise   = (const float*)d_in[1];
    const int*   el      = (const int*)d_in[2];
    float* out = (float*)d_out;

    int n_locs  = in_sizes[0] / EMB;
    int n_edges = in_sizes[2];

    // workspace layout (all 16B-aligned)
    char* w = (char*)d_ws;
    int*  cnt  = (int*)w;                 w += (size_t)n_locs * sizeof(int);
    int*  part = (int*)w;                 w += 4096 * sizeof(int);
    int*  offs = (int*)w;                 w += (size_t)n_locs * sizeof(int);
    int2* meta = (int2*)w;                w += (size_t)n_locs * sizeof(int2);
    int*  rank = (int*)w;                 w += (size_t)n_edges * sizeof(int);
    int*  csr  = (int*)w;

    int nb = (n_locs + 255) / 256;

    (void)hipMemsetAsync(cnt, 0, (size_t)n_locs * sizeof(int), stream);

    count_rank_k<<<(n_edges + 255) / 256, 256, 0, stream>>>(el, cnt, rank, n_edges);
    block_sum_k<<<nb, 256, 0, stream>>>(cnt, part, n_locs);
    scan_part_k<<<1, 1024, 0, stream>>>(part, nb);
    scan_meta_k<<<nb, 256, 0, stream>>>(cnt, part, offs, meta, n_locs);
    fill_csr_k<<<(n_edges + 255) / 256, 256, 0, stream>>>(el, rank, offs, csr, n_edges);

    double sigma = 1.0 * sqrt(2.0 * log(1.25 / 1e-5)) / 1.0;
    long long total = (long long)n_locs * 16;
    int blocks = (int)((total + 255) / 256);
    gather_k<<<blocks, 256, 0, stream>>>(loc_emb, noise, meta, csr, out,
                                         (float)sigma, n_locs);
}